// Round 4
// baseline (332.608 us; speedup 1.0000x reference)
//
#include <hip/hip_runtime.h>
#include <math.h>

#define B_ 64
#define P_ 24564
#define G_ 48

// Workspace layout:
//   [0]   double              loss_sum
//   [8]   unsigned int        npos
//   [12]  pad
//   [16]  unsigned long long  bpk[B_*G_]         zeroed each call (atomicMax)
//   [16+B_*G_*8] unsigned short mrec[B_*PAD_P]   fully overwritten each call
// Total ~3.03 MB.

constexpr int CH    = 1024;             // priors per K1 block
constexpr int NCH   = 24;               // 24*1024 = 24576 >= P_
constexpr int PAD_P = NCH * CH;         // 24576
constexpr int PPT   = 4;                // priors per thread in K1

__device__ __forceinline__ float frcp(float x) { return __builtin_amdgcn_rcpf(x); }

// ---------------- K1: fused match — per-prior top-2 + per-gt global argmax -----------------
__global__ __launch_bounds__(256) void match_kernel(
    const float* __restrict__ priors, const float* __restrict__ gt,
    unsigned long long* __restrict__ bpk, unsigned short* __restrict__ mrec) {
    const int b    = blockIdx.y;
    const int base = blockIdx.x * CH;
    const int tid  = threadIdx.x;

    __shared__ float4 sbox[G_];
    __shared__ float  sga[G_];
    __shared__ unsigned int swin[G_][4];
    if (tid < G_) {
        const float* q = gt + ((size_t)b * G_ + tid) * 5;
        float x1 = q[0], y1 = q[1], x2 = q[2], y2 = q[3];
        sbox[tid] = make_float4(x1, y1, x2, y2);
        sga[tid]  = (x2 - x1) * (y2 - y1);
    }
    __syncthreads();

    // load PPT priors (clamped OOB: duplicates prior P_-1; tie-break keeps the real one)
    float px1[PPT], py1[PPT], px2[PPT], py2[PPT], pa[PPT];
    unsigned int tb[PPT];  // 1023 - local_p  (per-gt tie-break: lower p wins)
#pragma unroll
    for (int j = 0; j < PPT; j++) {
        int lp = tid + 256 * j;
        int pc = min(base + lp, P_ - 1);
        float4 pr = ((const float4*)priors)[pc];
        float hx = pr.z * 0.5f, hy = pr.w * 0.5f;
        px1[j] = pr.x - hx; py1[j] = pr.y - hy;
        px2[j] = pr.x + hx; py2[j] = pr.y + hy;
        pa[j] = (px2[j] - px1[j]) * (py2[j] - py1[j]);
        tb[j] = (unsigned)(1023 - lp);
    }

    unsigned int k1[PPT], k2[PPT];  // per-prior top-2 packed keys (v_bits&~0x3F | 63-g)
#pragma unroll
    for (int j = 0; j < PPT; j++) { k1[j] = 0u; k2[j] = 0u; }
    unsigned int kg[G_];            // per-gt best over this thread's priors (packed)

    // main loop: DS-free except one b128+b32 read per g; fully unrolled (kg[] in regs)
#pragma unroll
    for (int g = 0; g < G_; g++) {
        float4 gb = sbox[g];
        float  ga = sga[g];
        unsigned int gmax = 0u;
#pragma unroll
        for (int j = 0; j < PPT; j++) {
            float ix1 = fmaxf(gb.x, px1[j]), iy1 = fmaxf(gb.y, py1[j]);
            float ix2 = fminf(gb.z, px2[j]), iy2 = fminf(gb.w, py2[j]);
            float iw = fmaxf(ix2 - ix1, 0.0f), ih = fmaxf(iy2 - iy1, 0.0f);
            float inter = iw * ih;
            float v = inter * frcp(ga + pa[j] - inter);
            unsigned int vb = __float_as_uint(v);
            unsigned int pk = (vb & 0xFFFFFFC0u) | (unsigned)(63 - g);
            k2[j] = max(k2[j], min(k1[j], pk));
            k1[j] = max(k1[j], pk);
            unsigned int gk = (vb & 0xFFFFFC00u) | tb[j];
            gmax = max(gmax, gk);
        }
        kg[g] = gmax;
    }

    // per-gt: wave reduce -> LDS -> exact recompute -> global atomicMax
    const int lane = tid & 63, wv = tid >> 6;
#pragma unroll
    for (int g = 0; g < G_; g++) {
        unsigned int v = kg[g];
        for (int off = 32; off; off >>= 1) {
            unsigned int o = __shfl_down(v, off, 64);
            v = max(v, o);
        }
        if (lane == 0) swin[g][wv] = v;
    }
    __syncthreads();
    if (tid < G_) {
        unsigned int w = max(max(swin[tid][0], swin[tid][1]),
                             max(swin[tid][2], swin[tid][3]));
        int p = base + 1023 - (int)(w & 0x3FFu);
        p = min(p, P_ - 1);  // defensive; unreachable by tie-break argument
        float4 pr = ((const float4*)priors)[p];
        float hx = pr.z * 0.5f, hy = pr.w * 0.5f;
        float px1e = pr.x - hx, py1e = pr.y - hy;
        float px2e = pr.x + hx, py2e = pr.y + hy;
        float pae = (px2e - px1e) * (py2e - py1e);
        float4 gb = sbox[tid];
        float ix1 = fmaxf(gb.x, px1e), iy1 = fmaxf(gb.y, py1e);
        float ix2 = fminf(gb.z, px2e), iy2 = fminf(gb.w, py2e);
        float iw = fmaxf(ix2 - ix1, 0.0f), ih = fmaxf(iy2 - iy1, 0.0f);
        float inter = iw * ih;
        float v = inter * frcp(sga[tid] + pae - inter);
        unsigned long long key = ((unsigned long long)__float_as_uint(v) << 32) |
                                 (unsigned long long)(0xFFFFFFFFu - (unsigned)p);
        atomicMax(&bpk[(size_t)b * G_ + tid], key);
    }

    // store per-prior record: i1(6) | i2(6) | pos(1)
#pragma unroll
    for (int j = 0; j < PPT; j++) {
        unsigned int i1 = 63u - (k1[j] & 63u);
        unsigned int i2 = 63u - (k2[j] & 63u);
        unsigned int pos = (k1[j] >= 0x3F000000u) ? 1u : 0u;  // exact v1>=0.5 test
        mrec[(size_t)b * PAD_P + base + tid + 256 * j] =
            (unsigned short)(i1 | (i2 << 6) | (pos << 12));
    }
}

// ---------------- K2: override + decode + IOG + loss ----------------------------------------
__global__ __launch_bounds__(256) void loss_kernel(
    const float* __restrict__ pred_loc, const float* __restrict__ priors,
    const float* __restrict__ gt, const unsigned long long* __restrict__ bpk,
    const unsigned short* __restrict__ mrec,
    double* __restrict__ loss_sum, unsigned int* __restrict__ nposp) {
    const int b = blockIdx.y;
    const int p = blockIdx.x * 256 + threadIdx.x;

    __shared__ float4 sbox[G_];
    __shared__ float  sga[G_];
    __shared__ int    sbp[G_] __attribute__((aligned(16)));
    if (threadIdx.x < G_) {
        const float* q = gt + ((size_t)b * G_ + threadIdx.x) * 5;
        float x1 = q[0], y1 = q[1], x2 = q[2], y2 = q[3];
        sbox[threadIdx.x] = make_float4(x1, y1, x2, y2);
        sga[threadIdx.x]  = (x2 - x1) * (y2 - y1);
        sbp[threadIdx.x] =
            (int)(0xFFFFFFFFu - (unsigned)(bpk[(size_t)b * G_ + threadIdx.x] & 0xFFFFFFFFull));
    }
    __syncthreads();

    float contrib = 0.0f;
    unsigned int ispos = 0;
    if (p < P_) {
        unsigned int m = mrec[(size_t)b * PAD_P + p];
        int i1 = (int)(m & 63u), i2 = (int)((m >> 6) & 63u);
        bool pos = (m >> 12) & 1u;

        // override: ascending g, last write wins
        int bi = i1;
        bool ovr = false;
        const int4* sbp4 = (const int4*)sbp;
#pragma unroll
        for (int q4 = 0; q4 < G_ / 4; q4++) {
            int4 s = sbp4[q4];
            if (s.x == p) { bi = 4 * q4 + 0; ovr = true; }
            if (s.y == p) { bi = 4 * q4 + 1; ovr = true; }
            if (s.z == p) { bi = 4 * q4 + 2; ovr = true; }
            if (s.w == p) { bi = 4 * q4 + 3; ovr = true; }
        }
        pos = pos || ovr;

        if (pos) {
            ispos = 1;
            int ri = (bi == i1) ? i2 : i1;

            float4 pr = ((const float4*)priors)[p];
            float4 l  = ((const float4*)pred_loc)[(size_t)b * P_ + p];
            float cx = pr.x + l.x * 0.1f * pr.z;
            float cy = pr.y + l.y * 0.1f * pr.w;
            float w  = pr.z * expf(l.z * 0.2f);
            float h  = pr.w * expf(l.w * 0.2f);
            float dx1 = cx - w * 0.5f, dy1 = cy - h * 0.5f;
            float dx2 = cx + w * 0.5f, dy2 = cy + h * 0.5f;

            float4 rb = sbox[ri];
            float ix1 = fmaxf(rb.x, dx1), iy1 = fmaxf(rb.y, dy1);
            float ix2 = fminf(rb.z, dx2), iy2 = fminf(rb.w, dy2);
            float iw = fmaxf(ix2 - ix1, 0.0f), ih = fmaxf(iy2 - iy1, 0.0f);
            float inter = iw * ih;
            float iogv = inter * frcp(sga[ri] + 1e-7f);

            if (iogv < 0.95f) {
                if (iogv < 0.5f)
                    contrib = -logf(1.0f - iogv + 1e-7f);
                else
                    contrib = (iogv - 0.5f) * 2.0f + 0.69314718055994531f;  // -ln(0.5)
            }
        }
    }

    for (int off = 32; off; off >>= 1) {
        contrib += __shfl_down(contrib, off, 64);
        ispos   += __shfl_down(ispos, off, 64);
    }
    __shared__ float rs[4];
    __shared__ unsigned int rn[4];
    const int lane = threadIdx.x & 63, wv = threadIdx.x >> 6;
    if (lane == 0) { rs[wv] = contrib; rn[wv] = ispos; }
    __syncthreads();
    if (threadIdx.x == 0) {
        float s = rs[0] + rs[1] + rs[2] + rs[3];
        unsigned int n = rn[0] + rn[1] + rn[2] + rn[3];
        if (s != 0.0f) atomicAdd(loss_sum, (double)s);
        if (n) atomicAdd(nposp, n);
    }
}

// ---------------- K3: finalize ---------------------------------------------------------------
__global__ void finalize_kernel(const double* __restrict__ loss_sum,
                                const unsigned int* __restrict__ nposp,
                                float* __restrict__ out) {
    out[0] = (float)(loss_sum[0] / (double)nposp[0]);
}

extern "C" void kernel_launch(void* const* d_in, const int* in_sizes, int n_in,
                              void* d_out, int out_size, void* d_ws, size_t ws_size,
                              hipStream_t stream) {
    const float* pred_loc = (const float*)d_in[0];  // [B,P,4]
    const float* priors   = (const float*)d_in[1];  // [P,4]
    const float* gt       = (const float*)d_in[2];  // [B,G,5]
    float* out = (float*)d_out;

    double* loss_sum = (double*)d_ws;
    unsigned int* nposp = (unsigned int*)((char*)d_ws + 8);
    unsigned long long* bpk = (unsigned long long*)((char*)d_ws + 16);
    unsigned short* mrec = (unsigned short*)((char*)d_ws + 16 + (size_t)B_ * G_ * 8);

    hipMemsetAsync(d_ws, 0, 16 + (size_t)B_ * G_ * 8, stream);

    dim3 g1(NCH, B_);
    match_kernel<<<g1, 256, 0, stream>>>(priors, gt, bpk, mrec);

    dim3 g2((P_ + 255) / 256, B_);
    loss_kernel<<<g2, 256, 0, stream>>>(pred_loc, priors, gt, bpk, mrec, loss_sum, nposp);

    finalize_kernel<<<1, 1, 0, stream>>>(loss_sum, nposp, out);
}

// Round 5
// 126.416 us; speedup vs baseline: 2.6311x; 2.6311x over previous
//
#include <hip/hip_runtime.h>
#include <math.h>

#define B_ 64
#define P_ 24564
#define G_ 48

// Workspace layout (total ~3.18 MB):
//   [0]        unsigned long long bpk[B_*G_]      (memset to 0 each call; atomicMax)
//   [24576]    unsigned short mrec[B_*PAD_P]      i1|i2<<6|pos<<12, overwritten each call
//   [3170304]  float        pl[NBLK]              per-block loss partials (overwritten)
//   [3176448]  unsigned int pn[NBLK]              per-block npos partials (overwritten)
//   [3182592]  double       corrl[B_]             per-image corrections (overwritten)
//   [3183104]  unsigned int corrn[B_]
constexpr int CH    = 1024;
constexpr int NCH   = 24;               // 24*1024 = 24576 >= P_
constexpr int PAD_P = NCH * CH;
constexpr int PPT   = 4;
constexpr int NBLK  = NCH * B_;         // 1536
constexpr int ROW   = 260;              // kgrid row in u32 (padded; 1040B stride, 16B aligned)

__device__ __forceinline__ float frcp(float x) { return __builtin_amdgcn_rcpf(x); }

// Shared smooth-ln repulsion term: decode prior+loc, IOG vs gt box, piecewise loss.
// Used identically in K1 (default contribution) and K2 (correction) so values cancel.
__device__ __forceinline__ float loss_term(float4 pr, float4 l, float4 gb, float ga) {
    float cx = pr.x + l.x * 0.1f * pr.z;
    float cy = pr.y + l.y * 0.1f * pr.w;
    float w  = pr.z * expf(l.z * 0.2f);
    float h  = pr.w * expf(l.w * 0.2f);
    float dx1 = cx - w * 0.5f, dy1 = cy - h * 0.5f;
    float dx2 = cx + w * 0.5f, dy2 = cy + h * 0.5f;
    float ix1 = fmaxf(gb.x, dx1), iy1 = fmaxf(gb.y, dy1);
    float ix2 = fminf(gb.z, dx2), iy2 = fminf(gb.w, dy2);
    float iw = fmaxf(ix2 - ix1, 0.0f), ih = fmaxf(iy2 - iy1, 0.0f);
    float iogv = (iw * ih) * frcp(ga + 1e-7f);
    float r = 0.0f;
    if (iogv < 0.95f) {
        if (iogv < 0.5f)
            r = -logf(1.0f - iogv + 1e-7f);
        else
            r = (iogv - 0.5f) * 2.0f + 0.69314718055994531f;  // -ln(0.5)
    }
    return r;
}

// ---------------- K1: fused — top-2 per prior, per-gt argmax, default loss ------------------
__global__ __launch_bounds__(256) void match_kernel(
    const float* __restrict__ pred_loc, const float* __restrict__ priors,
    const float* __restrict__ gt, unsigned long long* __restrict__ bpk,
    unsigned short* __restrict__ mrec, float* __restrict__ pl, unsigned int* __restrict__ pn) {
    const int b    = blockIdx.y;
    const int base = blockIdx.x * CH;
    const int tid  = threadIdx.x;

    __shared__ float4 sbox[G_];
    __shared__ float  sga[G_];
    __shared__ unsigned int kgrid[G_ * ROW];   // per-gt candidate keys, [g][tid]
    __shared__ unsigned int pmax[G_][4];
    __shared__ float rs[4];
    __shared__ unsigned int rn[4];

    if (tid < G_) {
        const float* q = gt + ((size_t)b * G_ + tid) * 5;
        float x1 = q[0], y1 = q[1], x2 = q[2], y2 = q[3];
        sbox[tid] = make_float4(x1, y1, x2, y2);
        sga[tid]  = (x2 - x1) * (y2 - y1);
    }
    __syncthreads();

    float px1[PPT], py1[PPT], px2[PPT], py2[PPT], pa[PPT];
    unsigned int tb[PPT];  // 1023 - local_p (per-gt tie-break: lower p wins)
#pragma unroll
    for (int j = 0; j < PPT; j++) {
        int lp = tid + 256 * j;
        int pc = min(base + lp, P_ - 1);  // clamped OOB dup loses tie-break to the real one
        float4 pr = ((const float4*)priors)[pc];
        float hx = pr.z * 0.5f, hy = pr.w * 0.5f;
        px1[j] = pr.x - hx; py1[j] = pr.y - hy;
        px2[j] = pr.x + hx; py2[j] = pr.y + hy;
        pa[j] = (px2[j] - px1[j]) * (py2[j] - py1[j]);
        tb[j] = (unsigned)(1023 - lp);
    }

    unsigned int k1[PPT], k2[PPT];  // packed top-2: (v&~0x3F) | (63-g)
#pragma unroll
    for (int j = 0; j < PPT; j++) { k1[j] = 0u; k2[j] = 0u; }

#pragma unroll 8
    for (int g = 0; g < G_; g++) {
        float4 gb = sbox[g];
        float  ga = sga[g];
        unsigned int gmax = 0u;
#pragma unroll
        for (int j = 0; j < PPT; j++) {
            float ix1 = fmaxf(gb.x, px1[j]), iy1 = fmaxf(gb.y, py1[j]);
            float ix2 = fminf(gb.z, px2[j]), iy2 = fminf(gb.w, py2[j]);
            float iw = fmaxf(ix2 - ix1, 0.0f), ih = fmaxf(iy2 - iy1, 0.0f);
            float inter = iw * ih;
            float v = inter * frcp(ga + pa[j] - inter);
            unsigned int vb = __float_as_uint(v);
            unsigned int pk = (vb & 0xFFFFFFC0u) | (unsigned)(63 - g);
            k2[j] = max(k2[j], min(k1[j], pk));
            k1[j] = max(k1[j], pk);
            unsigned int gk = (vb & 0xFFFFFC00u) | tb[j];
            gmax = max(gmax, gk);
        }
        kgrid[g * ROW + tid] = gmax;   // bank = (4g + tid) % 32 -> 2 lanes/bank, free
    }

    // per-prior epilogue: default contribution assumes NO override (bi=i1 -> rep=i2)
    float contrib = 0.0f;
    unsigned int np = 0;
#pragma unroll
    for (int j = 0; j < PPT; j++) {
        int p = base + tid + 256 * j;
        unsigned int i1 = 63u - (k1[j] & 63u);
        unsigned int i2 = 63u - (k2[j] & 63u);
        unsigned int pos = (k1[j] >= 0x3F000000u) ? 1u : 0u;  // exact v1>=0.5
        mrec[(size_t)b * PAD_P + base + tid + 256 * j] =
            (unsigned short)(i1 | (i2 << 6) | (pos << 12));
        if (p < P_ && pos) {
            float4 pr = ((const float4*)priors)[p];               // L1-hot reload
            float4 l  = ((const float4*)pred_loc)[(size_t)b * P_ + p];
            contrib += loss_term(pr, l, sbox[i2], sga[i2]);
            np++;
        }
    }

    // wave-level reduce of contrib/np
    const int lane = tid & 63, wv = tid >> 6;
    for (int off = 32; off; off >>= 1) {
        contrib += __shfl_down(contrib, off, 64);
        np      += __shfl_down(np, off, 64);
    }
    if (lane == 0) { rs[wv] = contrib; rn[wv] = np; }
    __syncthreads();  // kgrid + rs/rn visible

    // per-gt argmax: 4 readers per gt scan 64 entries each
    if (tid < 192) {
        int g = tid >> 2, qq = tid & 3;
        const uint4* row = (const uint4*)&kgrid[g * ROW + qq * 64];
        unsigned int m = 0u;
#pragma unroll 4
        for (int i = 0; i < 16; i++) {
            uint4 v = row[i];
            m = max(max(m, v.x), max(v.y, max(v.z, v.w)));
        }
        pmax[g][qq] = m;
    }
    __syncthreads();

    if (tid < G_) {
        unsigned int w = max(max(pmax[tid][0], pmax[tid][1]),
                             max(pmax[tid][2], pmax[tid][3]));
        int p = base + 1023 - (int)(w & 0x3FFu);
        p = min(p, P_ - 1);  // defensive; unreachable via tie-break
        float4 pr = ((const float4*)priors)[p];
        float hx = pr.z * 0.5f, hy = pr.w * 0.5f;
        float qx1 = pr.x - hx, qy1 = pr.y - hy, qx2 = pr.x + hx, qy2 = pr.y + hy;
        float pae = (qx2 - qx1) * (qy2 - qy1);
        float4 gb = sbox[tid];
        float ix1 = fmaxf(gb.x, qx1), iy1 = fmaxf(gb.y, qy1);
        float ix2 = fminf(gb.z, qx2), iy2 = fminf(gb.w, qy2);
        float iw = fmaxf(ix2 - ix1, 0.0f), ih = fmaxf(iy2 - iy1, 0.0f);
        float inter = iw * ih;
        float v = inter * frcp(sga[tid] + pae - inter);   // exact key for cross-block compare
        unsigned long long key = ((unsigned long long)__float_as_uint(v) << 32) |
                                 (unsigned long long)(0xFFFFFFFFu - (unsigned)p);
        atomicMax(&bpk[(size_t)b * G_ + tid], key);
    }

    if (tid == 0) {
        pl[b * NCH + blockIdx.x] = rs[0] + rs[1] + rs[2] + rs[3];
        pn[b * NCH + blockIdx.x] = rn[0] + rn[1] + rn[2] + rn[3];
    }
}

// ---------------- K2: per-gt override corrections (B_ x G_ work) ----------------------------
__global__ __launch_bounds__(64) void fix_kernel(
    const float* __restrict__ pred_loc, const float* __restrict__ priors,
    const float* __restrict__ gt, const unsigned long long* __restrict__ bpk,
    const unsigned short* __restrict__ mrec,
    double* __restrict__ corrl, unsigned int* __restrict__ corrn) {
    const int b = blockIdx.x, g = threadIdx.x;
    __shared__ int sp[G_];
    int p = -1;
    if (g < G_) {
        p = (int)(0xFFFFFFFFu - (unsigned)(bpk[(size_t)b * G_ + g] & 0xFFFFFFFFull));
        sp[g] = p;
    }
    __syncthreads();

    double delta = 0.0;
    unsigned int dn = 0;
    if (g < G_) {
        // last-write-wins: g is alive iff no larger g' shares the same best prior
        bool alive = true;
        for (int d = 1; d < G_; d++) {
            int t2 = g + d;
            if (t2 < G_ && sp[t2] == p) alive = false;
        }
        if (alive) {
            unsigned int m = mrec[(size_t)b * PAD_P + p];
            int i1 = (int)(m & 63u), i2 = (int)((m >> 6) & 63u);
            bool pos0 = (m >> 12) & 1u;
            int ri = (g == i1) ? i2 : i1;   // override: bi=g -> rep gt flips to i1 unless g==i1
            float4 pr = ((const float4*)priors)[p];
            float4 l  = ((const float4*)pred_loc)[(size_t)b * P_ + p];
            const float* qr = gt + ((size_t)b * G_ + ri) * 5;
            float4 gbr = make_float4(qr[0], qr[1], qr[2], qr[3]);
            float gar = (qr[2] - qr[0]) * (qr[3] - qr[1]);
            float cnew = loss_term(pr, l, gbr, gar);
            float cold = 0.0f;
            if (pos0) {
                const float* q2 = gt + ((size_t)b * G_ + i2) * 5;
                float4 gb2 = make_float4(q2[0], q2[1], q2[2], q2[3]);
                float ga2 = (q2[2] - q2[0]) * (q2[3] - q2[1]);
                cold = loss_term(pr, l, gb2, ga2);   // cancels K1's default term
            } else {
                dn = 1;                               // prior newly positive
            }
            delta = (double)cnew - (double)cold;
        }
    }
    for (int off = 32; off; off >>= 1) {
        delta += __shfl_down(delta, off, 64);
        dn    += __shfl_down(dn, off, 64);
    }
    if (g == 0) { corrl[b] = delta; corrn[b] = dn; }
}

// ---------------- K3: final reduction --------------------------------------------------------
__global__ __launch_bounds__(256) void final_kernel(
    const float* __restrict__ pl, const unsigned int* __restrict__ pn,
    const double* __restrict__ corrl, const unsigned int* __restrict__ corrn,
    float* __restrict__ out) {
    const int tid = threadIdx.x;
    double acc = 0.0;
    unsigned int n = 0;
    for (int i = tid; i < NBLK; i += 256) { acc += (double)pl[i]; n += pn[i]; }
    if (tid < B_) { acc += corrl[tid]; n += corrn[tid]; }
    for (int off = 32; off; off >>= 1) {
        acc += __shfl_down(acc, off, 64);
        n   += __shfl_down(n, off, 64);
    }
    __shared__ double ds[4];
    __shared__ unsigned int dns[4];
    const int lane = tid & 63, wv = tid >> 6;
    if (lane == 0) { ds[wv] = acc; dns[wv] = n; }
    __syncthreads();
    if (tid == 0) {
        double s = ds[0] + ds[1] + ds[2] + ds[3];
        unsigned int nn = dns[0] + dns[1] + dns[2] + dns[3];
        out[0] = (float)(s / (double)nn);
    }
}

extern "C" void kernel_launch(void* const* d_in, const int* in_sizes, int n_in,
                              void* d_out, int out_size, void* d_ws, size_t ws_size,
                              hipStream_t stream) {
    const float* pred_loc = (const float*)d_in[0];  // [B,P,4]
    const float* priors   = (const float*)d_in[1];  // [P,4]
    const float* gt       = (const float*)d_in[2];  // [B,G,5]
    float* out = (float*)d_out;

    char* ws = (char*)d_ws;
    unsigned long long* bpk = (unsigned long long*)ws;                    // 24576 B
    unsigned short* mrec = (unsigned short*)(ws + 24576);                 // 3145728 B
    float*        pl    = (float*)(ws + 3170304);                         // 6144 B
    unsigned int* pn    = (unsigned int*)(ws + 3176448);                  // 6144 B
    double*       corrl = (double*)(ws + 3182592);                        // 512 B
    unsigned int* corrn = (unsigned int*)(ws + 3183104);                  // 256 B

    hipMemsetAsync(bpk, 0, (size_t)B_ * G_ * 8, stream);

    dim3 g1(NCH, B_);
    match_kernel<<<g1, 256, 0, stream>>>(pred_loc, priors, gt, bpk, mrec, pl, pn);

    fix_kernel<<<B_, 64, 0, stream>>>(pred_loc, priors, gt, bpk, mrec, corrl, corrn);

    final_kernel<<<1, 256, 0, stream>>>(pl, pn, corrl, corrn, out);
}